// Round 8
// baseline (158.078 us; speedup 1.0000x reference)
//
#include <hip/hip_runtime.h>

// Lovász-Softmax (B=1, C=3) — degenerate closed form (verified R1–R17, absmax=0):
//   loss = mean over present classes c of weight[c] * mean_{lab==c}(-log(softmax_c + 1e-8))
// R18 = WAVE-SPECIALIZED STAGING. Falsified so far: grid shape (512/1024/2048),
// uniform 2-deep pipeline (R14), per-stream phase skew (R15), nt removal (R16:
// -14 µs, restored), forced 15-load MLP batches (R17). No pipe saturated
// (HBM 28%, L3 ~10%, VALU 12%) => last untested structural lever is the
// 5-interleaved-cursors-per-wave pattern itself. Here: BLK=320 (5 waves),
// wave s reads ONLY stream s (5x1KB bursts from one contiguous 5KB region)
// into linear LDS (lane-stride-16 b128 = canonical conflict-free), barrier,
// all threads consume 5-tuples from LDS. One sequential cursor per wave —
// the same access structure as the 6.7 TB/s poison fills.
// err = log(e^za+e^zb+e^zc) - z_lab (R9-verified exact, absmax 0).

#define EPS 1e-8f
#define BLK 320          // 5 waves: wave s stages stream s
#define CHK 320          // float4 groups per chunk = 5 KB per stream
#define CHUNKS 6
#define GPB (CHK*CHUNKS) // 1920 groups per block

typedef float fx4 __attribute__((ext_vector_type(4)));
typedef int   ix4 __attribute__((ext_vector_type(4)));

#define NTL(p) __builtin_nontemporal_load(p)

__device__ __forceinline__ void px_acc(float za, float zb, float zc, int la, int lb,
                                       float& s0, float& s1, float& s2,
                                       float& n0, float& n1, float& n2)
{
    float ea = __expf(za);
    float eb = __expf(zb);
    float ec = __expf(zc);
    float d  = ea + eb + ec;
    float zl = (la != 0) ? zb : ((lb != 0) ? zc : za);
    float err = __logf(d) - zl;          // == -log(softmax_lab), eps dropped
    float f1 = (la != 0) ? 1.f : 0.f;
    float f2 = (lb != 0) ? 1.f : 0.f;
    float f0 = 1.f - f1 - f2;
    s0 += f0 * err;  s1 += f1 * err;  s2 += f2 * err;
    n0 += f0;        n1 += f1;        n2 += f2;
}

__global__ __launch_bounds__(BLK) void lovasz_reduce_kernel(
    const float* __restrict__ probas,   // [3, P] channel-major
    const int*   __restrict__ labels,   // [3, P] one-hot int32
    float* __restrict__ partial,        // ws: [6][nblocks] transposed partials
    int P4, int P, int nfull, int nblocks)
{
    const fx4* z0  = (const fx4*)(probas);
    const fx4* z1  = (const fx4*)(probas + (size_t)P);
    const fx4* z2  = (const fx4*)(probas + 2 * (size_t)P);
    const fx4* l1f = (const fx4*)(labels + (size_t)P);      // staged as raw 16B
    const fx4* l2f = (const fx4*)(labels + 2 * (size_t)P);
    const ix4* l1  = (const ix4*)(labels + (size_t)P);      // tail path (typed)
    const ix4* l2  = (const ix4*)(labels + 2 * (size_t)P);

    __shared__ fx4 lds[5][CHK];          // 25 KB, single-buffered

    float s0 = 0.f, s1 = 0.f, s2 = 0.f;
    float n0 = 0.f, n1 = 0.f, n2 = 0.f;

    const int t    = threadIdx.x;
    const int wave = t >> 6;
    const int lane = t & 63;

    if (blockIdx.x < nfull) {
        const int bb = blockIdx.x * GPB;
        // wave-uniform stream selection (uniform branch, no divergence)
        const fx4* src;
        if      (wave == 0) src = z0;
        else if (wave == 1) src = z1;
        else if (wave == 2) src = z2;
        else if (wave == 3) src = l1f;
        else                src = l2f;

        #pragma unroll 1
        for (int ch = 0; ch < CHUNKS; ++ch) {
            const int cb = bb + ch * CHK;
            // ---- stage: this wave reads 5 KB contiguous of ITS stream ----
            fx4 r0 = NTL(&src[cb + 0 * 64 + lane]);
            fx4 r1 = NTL(&src[cb + 1 * 64 + lane]);
            fx4 r2 = NTL(&src[cb + 2 * 64 + lane]);
            fx4 r3 = NTL(&src[cb + 3 * 64 + lane]);
            fx4 r4 = NTL(&src[cb + 4 * 64 + lane]);
            lds[wave][0 * 64 + lane] = r0;   // linear lane-stride-16: conflict-free b128
            lds[wave][1 * 64 + lane] = r1;
            lds[wave][2 * 64 + lane] = r2;
            lds[wave][3 * 64 + lane] = r3;
            lds[wave][4 * 64 + lane] = r4;
            __syncthreads();
            // ---- consume: thread t takes group cb+t ----
            {
                fx4 a = lds[0][t];
                fx4 b = lds[1][t];
                fx4 c = lds[2][t];
                ix4 u = *(ix4*)&lds[3][t];
                ix4 v = *(ix4*)&lds[4][t];
                px_acc(a.x, b.x, c.x, u.x, v.x, s0, s1, s2, n0, n1, n2);
                px_acc(a.y, b.y, c.y, u.y, v.y, s0, s1, s2, n0, n1, n2);
                px_acc(a.z, b.z, c.z, u.z, v.z, s0, s1, s2, n0, n1, n2);
                px_acc(a.w, b.w, c.w, u.w, v.w, s0, s1, s2, n0, n1, n2);
            }
            __syncthreads();                 // protect lds before next stage
        }
    } else {
        // tail block: direct-load path (rem = P4 - nfull*GPB groups)
        for (int i = blockIdx.x * GPB + t; i < P4; i += BLK) {
            fx4 a = NTL(&z0[i]);
            fx4 b = NTL(&z1[i]);
            fx4 c = NTL(&z2[i]);
            ix4 u = NTL(&l1[i]);
            ix4 v = NTL(&l2[i]);
            px_acc(a.x, b.x, c.x, u.x, v.x, s0, s1, s2, n0, n1, n2);
            px_acc(a.y, b.y, c.y, u.y, v.y, s0, s1, s2, n0, n1, n2);
            px_acc(a.z, b.z, c.z, u.z, v.z, s0, s1, s2, n0, n1, n2);
            px_acc(a.w, b.w, c.w, u.w, v.w, s0, s1, s2, n0, n1, n2);
        }
    }

    // wave (64-lane) shuffle reduction
    #pragma unroll
    for (int off = 32; off > 0; off >>= 1) {
        s0 += __shfl_down(s0, off);
        s1 += __shfl_down(s1, off);
        s2 += __shfl_down(s2, off);
        n0 += __shfl_down(n0, off);
        n1 += __shfl_down(n1, off);
        n2 += __shfl_down(n2, off);
    }

    __shared__ float red[6][5];
    if (lane == 0) {
        red[0][wave] = s0; red[1][wave] = s1; red[2][wave] = s2;
        red[3][wave] = n0; red[4][wave] = n1; red[5][wave] = n2;
    }
    __syncthreads();
    if (t < 6) {
        int k = t;
        partial[(size_t)k * nblocks + blockIdx.x] =
            red[k][0] + red[k][1] + red[k][2] + red[k][3] + red[k][4];
    }
}

__global__ __launch_bounds__(256) void lovasz_finalize_kernel(
    const float* __restrict__ partial, int nblocks,
    const float* __restrict__ probas, const int* __restrict__ labels,
    const float* __restrict__ weight, float* __restrict__ out,
    int P4, int P)
{
    float acc[6] = {0.f, 0.f, 0.f, 0.f, 0.f, 0.f};
    for (int b = threadIdx.x; b < nblocks; b += 256) {
        #pragma unroll
        for (int k = 0; k < 6; ++k)
            acc[k] += partial[(size_t)k * nblocks + b];
    }

    #pragma unroll
    for (int k = 0; k < 6; ++k)
        #pragma unroll
        for (int off = 32; off > 0; off >>= 1)
            acc[k] += __shfl_down(acc[k], off);

    __shared__ float red[6][4];
    int wave = threadIdx.x >> 6;
    int lane = threadIdx.x & 63;
    if (lane == 0) {
        #pragma unroll
        for (int k = 0; k < 6; ++k) red[k][wave] = acc[k];
    }
    __syncthreads();
    if (threadIdx.x == 0) {
        float s[6];
        #pragma unroll
        for (int k = 0; k < 6; ++k)
            s[k] = red[k][0] + red[k][1] + red[k][2] + red[k][3];
        // scalar tail (P % 4 != 0; empty for this shape)
        for (int i = 4 * P4; i < P; ++i) {
            px_acc(probas[i], probas[(size_t)P + i], probas[2 * (size_t)P + i],
                   labels[(size_t)P + i], labels[2 * (size_t)P + i],
                   s[0], s[1], s[2], s[3], s[4], s[5]);
        }
        float total = 0.f, cnt = 0.f;
        #pragma unroll
        for (int c = 0; c < 3; ++c) {
            if (s[3 + c] > 0.f) {
                total += weight[c] * s[c] / s[3 + c];
                cnt += 1.f;
            }
        }
        out[0] = (cnt > 0.f) ? total / cnt : 0.f;
    }
}

extern "C" void kernel_launch(void* const* d_in, const int* in_sizes, int n_in,
                              void* d_out, int out_size, void* d_ws, size_t ws_size,
                              hipStream_t stream) {
    const float* probas = (const float*)d_in[0];
    const float* weight = (const float*)d_in[1];
    const int*   labels = (const int*)d_in[2];
    float* partial = (float*)d_ws;

    int total = in_sizes[0];        // B*C*D*H*W with B=1, C=3
    int P  = total / 3;             // pixels = 6,291,456
    int P4 = P / 4;                 // 1,572,864 float4 groups
    int nfull = P4 / GPB;           // 819 fully-staged blocks
    int rem = P4 - nfull * GPB;     // 384 groups -> 1 tail block
    int nblocks = nfull + (rem ? 1 : 0);

    lovasz_reduce_kernel<<<nblocks, BLK, 0, stream>>>(probas, labels, partial,
                                                      P4, P, nfull, nblocks);
    lovasz_finalize_kernel<<<1, 256, 0, stream>>>(partial, nblocks, probas,
                                                  labels, weight, (float*)d_out,
                                                  P4, P);
}

// Round 9
// 153.568 us; speedup vs baseline: 1.0294x; 1.0294x over previous
//
#include <hip/hip_runtime.h>

// Lovász-Softmax (B=1, C=3) — degenerate closed form (verified R1–R18, absmax=0):
//   loss = mean over present classes c of weight[c] * mean_{lab==c}(-log(softmax_c + 1e-8))
// R19 = FINAL REVERT to best-measured config (R0/R11: 512 blk x 256 thr, GPT=12,
// nt loads, two-kernel). Session falsification set, each lever individually
// tested and null/negative vs this config:
//   - grid shape 512/1024/2048 (R0/R13: equal within noise)
//   - fused last-block-done finalize (R12: +14 µs)
//   - uniform 2-deep pipeline (R14: null)
//   - per-stream phase skew z0+4..l2+0 (R15: null)
//   - nt removal (R16: +14 µs — nt loads A/B-proven to avoid L1 thrash from
//     5 streams ≡ 0 mod 32 KB; kept)
//   - forced 15-load MLP batches + memory clobber (R17: null)
//   - wave-specialized single-cursor LDS staging (R18: +5 µs)
// Kernel runs ~36 µs vs ~20 µs HBM floor with NO pipe saturated (HBM ~28%,
// VALU 12%, LDS 0): the 5-interleaved-stream read pattern's fabric limit.
// Remaining wall time is harness workspace poison (2 x 46 µs fills @ 6.6 TB/s).
// err = log(e^za+e^zb+e^zc) - z_lab (R9-verified exact, absmax 0).

#define EPS 1e-8f
#define BLK 256
#define GPT 12         // float4 groups per thread
#define GPB (GPT*BLK)  // groups per block = 3072

typedef float fx4 __attribute__((ext_vector_type(4)));
typedef int   ix4 __attribute__((ext_vector_type(4)));

__device__ __forceinline__ void px_acc(float za, float zb, float zc, int la, int lb,
                                       float& s0, float& s1, float& s2,
                                       float& n0, float& n1, float& n2)
{
    float ea = __expf(za);
    float eb = __expf(zb);
    float ec = __expf(zc);
    float d  = ea + eb + ec;
    float zl = (la != 0) ? zb : ((lb != 0) ? zc : za);
    float err = __logf(d) - zl;          // == -log(softmax_lab), eps dropped
    float f1 = (la != 0) ? 1.f : 0.f;
    float f2 = (lb != 0) ? 1.f : 0.f;
    float f0 = 1.f - f1 - f2;
    s0 += f0 * err;  s1 += f1 * err;  s2 += f2 * err;
    n0 += f0;        n1 += f1;        n2 += f2;
}

__global__ __launch_bounds__(BLK) void lovasz_reduce_kernel(
    const float* __restrict__ probas,   // [3, P] channel-major
    const int*   __restrict__ labels,   // [3, P] one-hot int32
    float* __restrict__ partial,        // ws: [6][nblocks] transposed partials
    int P4, int P, int nfull, int nblocks)
{
    const fx4* z0 = (const fx4*)(probas);
    const fx4* z1 = (const fx4*)(probas + (size_t)P);
    const fx4* z2 = (const fx4*)(probas + 2 * (size_t)P);
    const ix4* l1 = (const ix4*)(labels + (size_t)P);
    const ix4* l2 = (const ix4*)(labels + 2 * (size_t)P);

    float s0 = 0.f, s1 = 0.f, s2 = 0.f;
    float n0 = 0.f, n1 = 0.f, n2 = 0.f;

    const int base = blockIdx.x * GPB + threadIdx.x;

    if (blockIdx.x < nfull) {
        #pragma unroll
        for (int j = 0; j < GPT; ++j) {
            int i = base + j * BLK;
            fx4 a = __builtin_nontemporal_load(&z0[i]);
            fx4 b = __builtin_nontemporal_load(&z1[i]);
            fx4 c = __builtin_nontemporal_load(&z2[i]);
            ix4 u = __builtin_nontemporal_load(&l1[i]);
            ix4 v = __builtin_nontemporal_load(&l2[i]);
            px_acc(a.x, b.x, c.x, u.x, v.x, s0, s1, s2, n0, n1, n2);
            px_acc(a.y, b.y, c.y, u.y, v.y, s0, s1, s2, n0, n1, n2);
            px_acc(a.z, b.z, c.z, u.z, v.z, s0, s1, s2, n0, n1, n2);
            px_acc(a.w, b.w, c.w, u.w, v.w, s0, s1, s2, n0, n1, n2);
        }
    } else {
        #pragma unroll
        for (int j = 0; j < GPT; ++j) {
            int i = base + j * BLK;
            if (i < P4) {
                fx4 a = __builtin_nontemporal_load(&z0[i]);
                fx4 b = __builtin_nontemporal_load(&z1[i]);
                fx4 c = __builtin_nontemporal_load(&z2[i]);
                ix4 u = __builtin_nontemporal_load(&l1[i]);
                ix4 v = __builtin_nontemporal_load(&l2[i]);
                px_acc(a.x, b.x, c.x, u.x, v.x, s0, s1, s2, n0, n1, n2);
                px_acc(a.y, b.y, c.y, u.y, v.y, s0, s1, s2, n0, n1, n2);
                px_acc(a.z, b.z, c.z, u.z, v.z, s0, s1, s2, n0, n1, n2);
                px_acc(a.w, b.w, c.w, u.w, v.w, s0, s1, s2, n0, n1, n2);
            }
        }
    }

    // wave (64-lane) shuffle reduction
    #pragma unroll
    for (int off = 32; off > 0; off >>= 1) {
        s0 += __shfl_down(s0, off);
        s1 += __shfl_down(s1, off);
        s2 += __shfl_down(s2, off);
        n0 += __shfl_down(n0, off);
        n1 += __shfl_down(n1, off);
        n2 += __shfl_down(n2, off);
    }

    __shared__ float red[6][4];
    int wave = threadIdx.x >> 6;
    int lane = threadIdx.x & 63;
    if (lane == 0) {
        red[0][wave] = s0; red[1][wave] = s1; red[2][wave] = s2;
        red[3][wave] = n0; red[4][wave] = n1; red[5][wave] = n2;
    }
    __syncthreads();
    if (threadIdx.x < 6) {
        int k = threadIdx.x;
        partial[(size_t)k * nblocks + blockIdx.x] =
            red[k][0] + red[k][1] + red[k][2] + red[k][3];
    }
}

__global__ __launch_bounds__(256) void lovasz_finalize_kernel(
    const float* __restrict__ partial, int nblocks,
    const float* __restrict__ probas, const int* __restrict__ labels,
    const float* __restrict__ weight, float* __restrict__ out,
    int P4, int P)
{
    float acc[6] = {0.f, 0.f, 0.f, 0.f, 0.f, 0.f};
    for (int b = threadIdx.x; b < nblocks; b += 256) {
        #pragma unroll
        for (int k = 0; k < 6; ++k)
            acc[k] += partial[(size_t)k * nblocks + b];
    }

    #pragma unroll
    for (int k = 0; k < 6; ++k)
        #pragma unroll
        for (int off = 32; off > 0; off >>= 1)
            acc[k] += __shfl_down(acc[k], off);

    __shared__ float red[6][4];
    int wave = threadIdx.x >> 6;
    int lane = threadIdx.x & 63;
    if (lane == 0) {
        #pragma unroll
        for (int k = 0; k < 6; ++k) red[k][wave] = acc[k];
    }
    __syncthreads();
    if (threadIdx.x == 0) {
        float s[6];
        #pragma unroll
        for (int k = 0; k < 6; ++k)
            s[k] = red[k][0] + red[k][1] + red[k][2] + red[k][3];
        // scalar tail (P % 4 != 0; empty for this shape)
        for (int i = 4 * P4; i < P; ++i) {
            px_acc(probas[i], probas[(size_t)P + i], probas[2 * (size_t)P + i],
                   labels[(size_t)P + i], labels[2 * (size_t)P + i],
                   s[0], s[1], s[2], s[3], s[4], s[5]);
        }
        float total = 0.f, cnt = 0.f;
        #pragma unroll
        for (int c = 0; c < 3; ++c) {
            if (s[3 + c] > 0.f) {
                total += weight[c] * s[c] / s[3 + c];
                cnt += 1.f;
            }
        }
        out[0] = (cnt > 0.f) ? total / cnt : 0.f;
    }
}

extern "C" void kernel_launch(void* const* d_in, const int* in_sizes, int n_in,
                              void* d_out, int out_size, void* d_ws, size_t ws_size,
                              hipStream_t stream) {
    const float* probas = (const float*)d_in[0];
    const float* weight = (const float*)d_in[1];
    const int*   labels = (const int*)d_in[2];
    float* partial = (float*)d_ws;

    int total = in_sizes[0];        // B*C*D*H*W with B=1, C=3
    int P  = total / 3;             // pixels = 6,291,456
    int P4 = P / 4;                 // 1,572,864 float4 groups
    int nfull = P4 / GPB;           // 512 fully-covered blocks (2/CU)
    int rem = P4 - nfull * GPB;
    int nblocks = nfull + (rem ? 1 : 0);

    lovasz_reduce_kernel<<<nblocks, BLK, 0, stream>>>(probas, labels, partial,
                                                      P4, P, nfull, nblocks);
    lovasz_finalize_kernel<<<1, 256, 0, stream>>>(partial, nblocks, probas,
                                                  labels, weight, (float*)d_out,
                                                  P4, P);
}